// Round 26
// baseline (170.700 us; speedup 1.0000x reference)
//
#include <hip/hip_runtime.h>
#include <hip/hip_bf16.h>
#include <stdint.h>

#define B_ 4
#define S_ 2048
#define D_ 1024
#define H_ 16
#define DH_ 64
#define BH_ 64
#define M_ 8192   // B_*S_

typedef __bf16 bf16;
typedef __attribute__((ext_vector_type(4))) __bf16 bf16x4;
typedef __attribute__((ext_vector_type(8))) __bf16 bf16x8;
typedef __attribute__((ext_vector_type(4))) float f32x4;
typedef __attribute__((ext_vector_type(8))) float f32x8;

#define EXP2F(x) __builtin_amdgcn_exp2f(x)

__device__ inline void gload16(const void* g, void* l) {
  __builtin_amdgcn_global_load_lds((const __attribute__((address_space(1))) void*)g,
                                   (__attribute__((address_space(3))) void*)l, 16, 0, 0);
}

// ---------------- 1. W (DxD fp32) -> W^T (bf16), vectorized ----------------
__global__ __launch_bounds__(256) void k_wt(const float* __restrict__ wq,
    const float* __restrict__ wk, const float* __restrict__ wv, bf16* __restrict__ o) {
  __shared__ float t[32][132];
  int z = blockIdx.z;
  const float* w = z == 0 ? wq : (z == 1 ? wk : wv);
  bf16* d = o + (size_t)z * D_ * D_;
  int bn = blockIdx.x * 128;   // n (col of W) tile
  int bk = blockIdx.y * 32;    // k (row of W) tile
  int tid = threadIdx.x;
  int lc = (tid & 31) * 4, lk = tid >> 5;
#pragma unroll
  for (int j = 0; j < 4; j++) {
    f32x4 v = *(const f32x4*)&w[(size_t)(bk + lk + 8 * j) * D_ + bn + lc];
    *(f32x4*)&t[lk + 8 * j][lc] = v;
  }
  __syncthreads();
  int c = tid >> 1, kh = (tid & 1) * 16;
  bf16x8 r0, r1;
#pragma unroll
  for (int j = 0; j < 8; j++) {
    r0[j] = (bf16)t[kh + j][c];
    r1[j] = (bf16)t[kh + 8 + j][c];
  }
  *(bf16x8*)&d[(size_t)(bn + c) * D_ + bk + kh] = r0;
  *(bf16x8*)&d[(size_t)(bn + c) * D_ + bk + kh + 8] = r1;
}

// ---------------- 2. projection GEMM: X fp32 direct, BK=32, 128x128 ---------
// 3 blocks/CU (48KB dbuf) AND zero grid tail (1536 blocks = 2 exact waves of
// 768 resident) -- r23 had no tail but 1 blk/CU; r25 had 2 blk/CU but 1.5-wave
// tail. Addressing forms all r25-validated (A 128B-row XOR; B paired-row
// granule swizzle). 256 thr, 4 waves 2x2, per-wave 64x64. MFMA K-order
// unchanged -> bit-identical. z=0: Q (pre-scaled log2e/8); z=1: K; z=2: V^T.
__global__ __launch_bounds__(256, 4) void k_proj(const float* __restrict__ Xq,
    const float* __restrict__ Xk, const float* __restrict__ Xv,
    const bf16* __restrict__ WT, bf16* __restrict__ Qo, bf16* __restrict__ Ko,
    bf16* __restrict__ VTo) {
  __shared__ char lds[49152];  // buf[2] x { A fp32 [128][128B] | B bf16 paired [64][128B] }
  int z = blockIdx.z;
  const float* Xz = z == 0 ? Xq : (z == 1 ? Xk : Xv);
  const char* Ab = (const char*)Xz;
  const char* Bb = (const char*)(WT + (size_t)z * D_ * D_);
  int m0 = blockIdx.x * 128, n0 = blockIdx.y * 128;
  int tid = threadIdx.x, lane = tid & 63, w = tid >> 6;
  int wr = w >> 1, wc = w & 1, fr = lane & 15, fg = lane >> 4;
  f32x4 acc[4][4];
#pragma unroll
  for (int a = 0; a < 4; a++)
#pragma unroll
    for (int b = 0; b < 4; b++) acc[a][b] = (f32x4){0.f, 0.f, 0.f, 0.f};

  // prologue: stage K-step 0 into buf0 (6 rounds x 256 thr x 16B = 24KB)
#pragma unroll
  for (int it = 0; it < 6; ++it) {
    int ow = (w + 4 * it) * 1024;
    int o = ow + lane * 16;
    const char* src;
    if (o < 16384) {                 // A (fp32, 128 B/row)
      int row = o >> 7;
      int db = (o & 127) ^ ((row & 7) << 4);
      src = Ab + (size_t)(m0 + row) * 4096 + db;
    } else {                         // B (bf16, paired 128B rows)
      int lo = o - 16384;
      int p = lo >> 7;
      int g0 = ((lo & 127) >> 4) ^ (p & 7);
      int n = p * 2 + (g0 >> 2);
      int kbyte = (g0 & 3) * 16 + (lo & 15);
      src = Bb + (size_t)(n0 + n) * 2048 + kbyte;
    }
    gload16(src, lds + ow);
  }

#pragma unroll 2
  for (int t = 0; t < 32; ++t) {
    __syncthreads();            // drains STAGE(t); prior reads of buf^1 done
    if (t + 1 < 32) {           // stage next K-step; lands during compute below
      const int nb = ((t + 1) & 1) ? 24576 : 0;
      const int k0 = (t + 1) * 32;
#pragma unroll
      for (int it = 0; it < 6; ++it) {
        int ow = (w + 4 * it) * 1024;
        int o = ow + lane * 16;
        const char* src;
        if (o < 16384) {
          int row = o >> 7;
          int db = (o & 127) ^ ((row & 7) << 4);
          src = Ab + (size_t)(m0 + row) * 4096 + k0 * 4 + db;
        } else {
          int lo = o - 16384;
          int p = lo >> 7;
          int g0 = ((lo & 127) >> 4) ^ (p & 7);
          int n = p * 2 + (g0 >> 2);
          int kbyte = (g0 & 3) * 16 + (lo & 15);
          src = Bb + (size_t)(n0 + n) * 2048 + k0 * 2 + kbyte;
        }
        gload16(src, lds + nb + ow);
      }
    }
    const int cb = (t & 1) ? 24576 : 0;   // compile-time under unroll 2
    bf16x8 af[4], bfr[4];
#pragma unroll
    for (int mi = 0; mi < 4; mi++) {
      int row = wr * 64 + mi * 16 + fr;
      int kb = fg * 32;
      int sx = (row & 7) << 4;
      f32x4 a0 = *(const f32x4*)(lds + cb + row * 128 + (kb ^ sx));
      f32x4 a1 = *(const f32x4*)(lds + cb + row * 128 + ((kb + 16) ^ sx));
      bf16x8 v;
#pragma unroll
      for (int j = 0; j < 4; j++) { v[j] = (bf16)a0[j]; v[4 + j] = (bf16)a1[j]; }
      af[mi] = v;
    }
#pragma unroll
    for (int ni = 0; ni < 4; ni++) {
      int row = wc * 64 + ni * 16 + fr;
      int p = row >> 1;
      int g = (((row & 1) << 2) + fg) ^ (p & 7);
      bfr[ni] = *(const bf16x8*)(lds + cb + 16384 + p * 128 + (g << 4));
    }
#pragma unroll
    for (int mi = 0; mi < 4; mi++)
#pragma unroll
      for (int ni = 0; ni < 4; ni++)
        acc[mi][ni] = __builtin_amdgcn_mfma_f32_16x16x32_bf16(af[mi], bfr[ni],
                                                              acc[mi][ni], 0, 0, 0);
  }
  if (z == 2) {
    // V epilogue: VT[bh][d][blk*64 + slot], slot = sigma^-1(key); key low2 = r
#pragma unroll
    for (int mi = 0; mi < 4; mi++) {
      int row = m0 + wr * 64 + mi * 16 + 4 * fg;   // r = 0 base
      int bI = row >> 11, s = row & 2047;
      int blk = s >> 6, kk = s & 63;
      int slot = (kk & 0x23) | ((kk & 0x0C) << 1) | ((kk & 0x10) >> 2);
#pragma unroll
      for (int ni = 0; ni < 4; ni++) {
        int col = n0 + wc * 64 + ni * 16 + fr;
        int h = col >> 6, d = col & 63;
        bf16x4 vv = (bf16x4){(bf16)acc[mi][ni][0], (bf16)acc[mi][ni][1],
                             (bf16)acc[mi][ni][2], (bf16)acc[mi][ni][3]};
        *(bf16x4*)&VTo[((size_t)(bI * H_ + h) * DH_ + d) * S_ + blk * 64 + slot] = vv;
      }
    }
  } else {
    bf16* O = z == 0 ? Qo : Ko;
    // Q: fold 1/sqrt(dh) AND log2(e) so softmax can use exp2 directly.
    float sc = (z == 0) ? 0.18033688011112042f : 1.0f;
#pragma unroll
    for (int mi = 0; mi < 4; mi++)
#pragma unroll
      for (int r = 0; r < 4; r++) {
        int row = m0 + wr * 64 + mi * 16 + 4 * fg + r;
        int b = row >> 11, s = row & 2047;
#pragma unroll
        for (int ni = 0; ni < 4; ni++) {
          int col = n0 + wc * 64 + ni * 16 + fr;
          int h = col >> 6, d = col & 63;
          O[((size_t)(b * H_ + h) * S_ + s) * DH_ + d] = (bf16)(acc[mi][ni][r] * sc);
        }
      }
  }
}

// ---------------- 3. flash attention (r12/r19-exact: measured 84.7us) -------
// 8 waves x 32 q-rows (block = 256 q, grid 512). KBLK=64, guarded dbuf
// staging, unroll-2 static offsets, defer-max (THR=7) per mi, l via
// ones-MFMA, v_max3 tree. XCD-swizzled (512 % 8 == 0).
__global__ __launch_bounds__(512, 4) void k_attn(const bf16* __restrict__ Q,
    const bf16* __restrict__ Kt, const bf16* __restrict__ VT, float* __restrict__ out) {
  __shared__ bf16 kv[16384];    // 32KB: buf0 [0,8192) K | [8192] V ; buf1 at +8192 elems
  int g = blockIdx.x;
  int wg = (g & 7) * 64 + (g >> 3);    // 512 % 8 == 0 -> bijective
  int qt = wg & 7, bh = wg >> 3;
  int b = bh >> 4, h = bh & 15;
  int tid = threadIdx.x, lane = tid & 63, w = tid >> 6;
  int fr = lane & 15, fg = lane >> 4;
  const char* Kb = (const char*)(Kt + (size_t)bh * S_ * DH_);
  const char* Vb = (const char*)(VT + (size_t)bh * DH_ * S_);
  int q0 = qt * 256 + w * 32;

  // per-thread staging sources (512 thr x 16B = 8KB per region per round)
  int o0 = tid * 16;                       // byte offset within region [0,8192)
  int r0 = o0 >> 7, b0 = (o0 & 127) ^ ((r0 & 7) << 4);
  const char* kp = Kb + r0 * 128 + b0;     // +8192 B/tile
  const char* vp = Vb + r0 * 4096 + b0;    // +128 B/tile
  char* lb = (char*)kv;
  int w1024 = w * 1024;                    // wave-uniform LDS dest base

  // hoisted LDS read bases: row = {ks,ds}*16 + fr -> row&7 == fr&7 loop-inv.
  const int swz = (fr & 7) << 3;
  const bf16* kb0 = &kv[fr * 64 + ((fg * 8) ^ swz)];
  const bf16* kb1 = &kv[fr * 64 + ((fg * 8 + 32) ^ swz)];
  const bf16* vb0 = kb0 + 4096;
  const bf16* vb1 = kb1 + 4096;

  bf16x8 qf[2][2];
#pragma unroll
  for (int mi = 0; mi < 2; mi++)
#pragma unroll
    for (int c = 0; c < 2; c++)
      qf[mi][c] = *(const bf16x8*)(Q + ((size_t)bh * S_ + q0 + mi * 16 + fr) * DH_ + fg * 8 + 32 * c);
  float m_[2] = {-1e30f, -1e30f};
  f32x4 o_[2][4];
#pragma unroll
  for (int mi = 0; mi < 2; mi++)
#pragma unroll
    for (int ds = 0; ds < 4; ds++) o_[mi][ds] = (f32x4){0.f, 0.f, 0.f, 0.f};
  f32x4 ol[2] = {(f32x4){0.f, 0.f, 0.f, 0.f}, (f32x4){0.f, 0.f, 0.f, 0.f}};
  bf16x8 vones;
#pragma unroll
  for (int j = 0; j < 8; j++) vones[j] = (bf16)1.0f;

  // prologue: stage tile 0 into buf0
  gload16(kp, lb + w1024);
  gload16(vp, lb + 8192 + w1024);
  kp += 8192; vp += 128;

#pragma unroll 2
  for (int kt = 0; kt < 32; ++kt) {
    __syncthreads();            // drains STAGE(kt); prior reads of buf^1 done
    if (kt + 1 < 32) {          // stage next tile; lands during compute below
      const int nb = ((kt + 1) & 1) << 14;
      gload16(kp, lb + nb + w1024);
      gload16(vp, lb + nb + 8192 + w1024);
      kp += 8192; vp += 128;
    }
    const int cb = (kt & 1) << 13;   // elems; compile-time under unroll 2
    // swapped QK^T: st[mi][ks] = D[key][q], col=q=fr, key = 16ks + 4fg + r
    f32x4 st[2][4];
    __builtin_amdgcn_s_setprio(1);
#pragma unroll
    for (int ks = 0; ks < 4; ks++) {
      bf16x8 kf0 = *(const bf16x8*)(kb0 + cb + ks * 1024);
      bf16x8 kf1 = *(const bf16x8*)(kb1 + cb + ks * 1024);
#pragma unroll
      for (int mi = 0; mi < 2; mi++) {
        f32x4 a = (f32x4){0.f, 0.f, 0.f, 0.f};
        a = __builtin_amdgcn_mfma_f32_16x16x32_bf16(kf0, qf[mi][0], a, 0, 0, 0);
        a = __builtin_amdgcn_mfma_f32_16x16x32_bf16(kf1, qf[mi][1], a, 0, 0, 0);
        st[mi][ks] = a;
      }
    }
    __builtin_amdgcn_s_setprio(0);
    // per-mi online softmax with defer-max (T13), v_max3 tree (T17)
    bf16x8 pa[2][2];
#pragma unroll
    for (int mi = 0; mi < 2; mi++) {
      float ma = fmaxf(fmaxf(st[mi][0][0], st[mi][0][1]), st[mi][0][2]);
      float mb = fmaxf(fmaxf(st[mi][0][3], st[mi][1][0]), st[mi][1][1]);
      float mc = fmaxf(fmaxf(st[mi][1][2], st[mi][1][3]), st[mi][2][0]);
      float md = fmaxf(fmaxf(st[mi][2][1], st[mi][2][2]), st[mi][2][3]);
      float me = fmaxf(fmaxf(st[mi][3][0], st[mi][3][1]), st[mi][3][2]);
      float mx = fmaxf(fmaxf(fmaxf(ma, mb), mc), fmaxf(fmaxf(md, me), st[mi][3][3]));
      mx = fmaxf(mx, __shfl_xor(mx, 16));
      mx = fmaxf(mx, __shfl_xor(mx, 32));
      if (!__all(mx - m_[mi] <= 7.0f)) {
        float mnew = fmaxf(m_[mi], mx);
        float sf = EXP2F(m_[mi] - mnew);
        m_[mi] = mnew;
        float s0 = __shfl(sf, 4 * fg + 0);
        float s1 = __shfl(sf, 4 * fg + 1);
        float s2 = __shfl(sf, 4 * fg + 2);
        float s3 = __shfl(sf, 4 * fg + 3);
#pragma unroll
        for (int ds = 0; ds < 4; ds++) {
          o_[mi][ds][0] *= s0; o_[mi][ds][1] *= s1;
          o_[mi][ds][2] *= s2; o_[mi][ds][3] *= s3;
        }
        ol[mi][0] *= s0; ol[mi][1] *= s1; ol[mi][2] *= s2; ol[mi][3] *= s3;
      }
#pragma unroll
      for (int ks = 0; ks < 4; ks++)
#pragma unroll
        for (int r = 0; r < 4; r++) st[mi][ks][r] = EXP2F(st[mi][ks][r] - m_[mi]);
      pa[mi][0] = (bf16x8){(bf16)st[mi][0][0], (bf16)st[mi][0][1], (bf16)st[mi][0][2],
                           (bf16)st[mi][0][3], (bf16)st[mi][1][0], (bf16)st[mi][1][1],
                           (bf16)st[mi][1][2], (bf16)st[mi][1][3]};
      pa[mi][1] = (bf16x8){(bf16)st[mi][2][0], (bf16)st[mi][2][1], (bf16)st[mi][2][2],
                           (bf16)st[mi][2][3], (bf16)st[mi][3][0], (bf16)st[mi][3][1],
                           (bf16)st[mi][3][2], (bf16)st[mi][3][3]};
    }
    // PV + row-sum(l) via ones-MFMA; V fragments SHARED across both mi
    __builtin_amdgcn_s_setprio(1);
#pragma unroll
    for (int mi = 0; mi < 2; mi++) {
      ol[mi] = __builtin_amdgcn_mfma_f32_16x16x32_bf16(pa[mi][0], vones, ol[mi], 0, 0, 0);
      ol[mi] = __builtin_amdgcn_mfma_f32_16x16x32_bf16(pa[mi][1], vones, ol[mi], 0, 0, 0);
    }
#pragma unroll
    for (int c = 0; c < 2; c++) {
      const bf16* vbc = c ? vb1 : vb0;
#pragma unroll
      for (int ds = 0; ds < 4; ds++) {
        bf16x8 vf = *(const bf16x8*)(vbc + cb + ds * 1024);
        o_[0][ds] = __builtin_amdgcn_mfma_f32_16x16x32_bf16(pa[0][c], vf, o_[0][ds], 0, 0, 0);
        o_[1][ds] = __builtin_amdgcn_mfma_f32_16x16x32_bf16(pa[1][c], vf, o_[1][ds], 0, 0, 0);
      }
    }
    __builtin_amdgcn_s_setprio(0);
  }
  // finalize: ol[mi][r] = l[q = q0+mi*16+4fg+r] (replicated over fr)
#pragma unroll
  for (int mi = 0; mi < 2; mi++)
#pragma unroll
    for (int r = 0; r < 4; r++) {
      float inv = 1.0f / ol[mi][r];
      int s = q0 + mi * 16 + 4 * fg + r;
#pragma unroll
      for (int ds = 0; ds < 4; ds++) {
        int col = h * DH_ + ds * 16 + fr;
        out[((size_t)b * S_ + s) * D_ + col] = o_[mi][ds][r] * inv;
      }
    }
}

extern "C" void kernel_launch(void* const* d_in, const int* in_sizes, int n_in,
                              void* d_out, int out_size, void* d_ws, size_t ws_size,
                              hipStream_t stream) {
  (void)in_sizes; (void)n_in; (void)out_size; (void)ws_size;
  const float* q  = (const float*)d_in[0];
  const float* k  = (const float*)d_in[1];
  const float* v  = (const float*)d_in[2];
  const float* wq = (const float*)d_in[3];
  const float* wk = (const float*)d_in[4];
  const float* wv = (const float*)d_in[5];
  float* out = (float*)d_out;
  char* ws = (char*)d_ws;
  size_t off = 0;
  bf16* wt = (bf16*)(ws + off); off += (size_t)3 * D_ * D_ * 2;    //  6.3 MB
  bf16* Qw = (bf16*)(ws + off); off += (size_t)BH_ * S_ * DH_ * 2; // 16.8 MB
  bf16* Kw = (bf16*)(ws + off); off += (size_t)BH_ * S_ * DH_ * 2;
  bf16* Vt = (bf16*)(ws + off); off += (size_t)BH_ * S_ * DH_ * 2;

  k_wt  <<<dim3(8, 32, 3), 256, 0, stream>>>(wq, wk, wv, wt);
  k_proj<<<dim3(64, 8, 3), 256, 0, stream>>>(q, k, v, wt, Qw, Kw, Vt);
  k_attn<<<dim3(512), 512, 0, stream>>>(Qw, Kw, Vt, out);
}

// Round 27
// 154.896 us; speedup vs baseline: 1.1020x; 1.1020x over previous
//
#include <hip/hip_runtime.h>
#include <hip/hip_bf16.h>
#include <stdint.h>

#define B_ 4
#define S_ 2048
#define D_ 1024
#define H_ 16
#define DH_ 64
#define BH_ 64
#define M_ 8192   // B_*S_

typedef __bf16 bf16;
typedef __attribute__((ext_vector_type(4))) __bf16 bf16x4;
typedef __attribute__((ext_vector_type(8))) __bf16 bf16x8;
typedef __attribute__((ext_vector_type(4))) float f32x4;
typedef __attribute__((ext_vector_type(8))) float f32x8;

#define EXP2F(x) __builtin_amdgcn_exp2f(x)

__device__ inline void gload16(const void* g, void* l) {
  __builtin_amdgcn_global_load_lds((const __attribute__((address_space(1))) void*)g,
                                   (__attribute__((address_space(3))) void*)l, 16, 0, 0);
}

// ---------------- 1. W (DxD fp32) -> W^T (bf16), vectorized ----------------
__global__ __launch_bounds__(256) void k_wt(const float* __restrict__ wq,
    const float* __restrict__ wk, const float* __restrict__ wv, bf16* __restrict__ o) {
  __shared__ float t[32][132];
  int z = blockIdx.z;
  const float* w = z == 0 ? wq : (z == 1 ? wk : wv);
  bf16* d = o + (size_t)z * D_ * D_;
  int bn = blockIdx.x * 128;   // n (col of W) tile
  int bk = blockIdx.y * 32;    // k (row of W) tile
  int tid = threadIdx.x;
  int lc = (tid & 31) * 4, lk = tid >> 5;
#pragma unroll
  for (int j = 0; j < 4; j++) {
    f32x4 v = *(const f32x4*)&w[(size_t)(bk + lk + 8 * j) * D_ + bn + lc];
    *(f32x4*)&t[lk + 8 * j][lc] = v;
  }
  __syncthreads();
  int c = tid >> 1, kh = (tid & 1) * 16;
  bf16x8 r0, r1;
#pragma unroll
  for (int j = 0; j < 8; j++) {
    r0[j] = (bf16)t[kh + j][c];
    r1[j] = (bf16)t[kh + 8 + j][c];
  }
  *(bf16x8*)&d[(size_t)(bn + c) * D_ + bk + kh] = r0;
  *(bf16x8*)&d[(size_t)(bn + c) * D_ + bk + kh + 8] = r1;
}

// ---------------- 2. projection GEMM: X fp32 direct, 2-phase dbuf -----------
// r23-exact (family optimum 155.9us): BK=64, 512 thr, 128m x 256n (8 waves
// 2x4, per-wave 64x64), buffer = A fp32 32KB + B bf16 32KB, dbuf 128KB.
// barrier -> STAGE(t+1, buf^1) -> compute(buf). fp32 A converted at fragment
// load (same cast as k_conv -> bit-identical). Sweep ledger: BK=32 variants
// (r24 conflicts, r25 neutral, r26 staging-overhead) all lose to this.
// z=0: Q (pre-scaled log2e/8); z=1: K; z=2: sigma-permuted V^T.
__global__ __launch_bounds__(512, 2) void k_proj(const float* __restrict__ Xq,
    const float* __restrict__ Xk, const float* __restrict__ Xv,
    const bf16* __restrict__ WT, bf16* __restrict__ Qo, bf16* __restrict__ Ko,
    bf16* __restrict__ VTo) {
  __shared__ char lds[131072];  // buf[2] x { A fp32 [128][256B] | B bf16 [256][128B] }
  int z = blockIdx.z;
  const float* Xz = z == 0 ? Xq : (z == 1 ? Xk : Xv);
  const char* Ab = (const char*)Xz;
  const char* Bb = (const char*)(WT + (size_t)z * D_ * D_);
  int m0 = blockIdx.x * 128, n0 = blockIdx.y * 256;
  int tid = threadIdx.x, lane = tid & 63, w = tid >> 6;
  int wr = w >> 2, wc = w & 3, fr = lane & 15, fg = lane >> 4;
  f32x4 acc[4][4];
#pragma unroll
  for (int a = 0; a < 4; a++)
#pragma unroll
    for (int b = 0; b < 4; b++) acc[a][b] = (f32x4){0.f, 0.f, 0.f, 0.f};

  // prologue: stage K-step 0 into buf0 (8 rounds x 512 thr x 16B = 64KB)
#pragma unroll
  for (int it = 0; it < 8; ++it) {
    int ow = (w + 8 * it) * 1024;
    int o = ow + lane * 16;
    const char* src;
    if (o < 32768) {                 // A (fp32, 256 B/row, 16B-gran XOR)
      int row = o >> 8;
      int db = (o & 255) ^ ((row & 15) << 4);
      src = Ab + (size_t)(m0 + row) * 4096 + db;
    } else {                         // B (bf16, 128 B/row)
      int lo = o - 32768, row = lo >> 7;
      int db = (lo & 127) ^ ((row & 7) << 4);
      src = Bb + (size_t)(n0 + row) * 2048 + db;
    }
    gload16(src, lds + ow);
  }

#pragma unroll 2
  for (int t = 0; t < 16; ++t) {
    __syncthreads();            // drains STAGE(t); prior reads of buf^1 done
    if (t + 1 < 16) {           // stage next K-step; lands during compute below
      const int nb = ((t + 1) & 1) << 16;
      const int k0 = (t + 1) * 64;
#pragma unroll
      for (int it = 0; it < 8; ++it) {
        int ow = (w + 8 * it) * 1024;
        int o = ow + lane * 16;
        const char* src;
        if (o < 32768) {
          int row = o >> 8;
          int db = (o & 255) ^ ((row & 15) << 4);
          src = Ab + (size_t)(m0 + row) * 4096 + k0 * 4 + db;
        } else {
          int lo = o - 32768, row = lo >> 7;
          int db = (lo & 127) ^ ((row & 7) << 4);
          src = Bb + (size_t)(n0 + row) * 2048 + k0 * 2 + db;
        }
        gload16(src, lds + nb + ow);
      }
    }
    const int cb = (t & 1) << 16;   // compile-time under unroll 2
#pragma unroll
    for (int c = 0; c < 2; c++) {
      bf16x8 af[4], bfr[4];
#pragma unroll
      for (int mi = 0; mi < 4; mi++) {
        int row = wr * 64 + mi * 16 + fr;
        int kb = fg * 32 + 128 * c;
        int sx = (row & 15) << 4;
        f32x4 a0 = *(const f32x4*)(lds + cb + row * 256 + (kb ^ sx));
        f32x4 a1 = *(const f32x4*)(lds + cb + row * 256 + ((kb + 16) ^ sx));
        bf16x8 v;
#pragma unroll
        for (int j = 0; j < 4; j++) { v[j] = (bf16)a0[j]; v[4 + j] = (bf16)a1[j]; }
        af[mi] = v;
      }
#pragma unroll
      for (int ni = 0; ni < 4; ni++) {
        int row = wc * 64 + ni * 16 + fr;
        bfr[ni] = *(const bf16x8*)(lds + cb + 32768 + row * 128 +
                                   ((fg * 16 + 64 * c) ^ ((row & 7) << 4)));
      }
#pragma unroll
      for (int mi = 0; mi < 4; mi++)
#pragma unroll
        for (int ni = 0; ni < 4; ni++)
          acc[mi][ni] = __builtin_amdgcn_mfma_f32_16x16x32_bf16(af[mi], bfr[ni],
                                                                acc[mi][ni], 0, 0, 0);
    }
  }
  if (z == 2) {
    // V epilogue: VT[bh][d][blk*64 + slot], slot = sigma^-1(key); key low2 = r
#pragma unroll
    for (int mi = 0; mi < 4; mi++) {
      int row = m0 + wr * 64 + mi * 16 + 4 * fg;   // r = 0 base
      int bI = row >> 11, s = row & 2047;
      int blk = s >> 6, kk = s & 63;
      int slot = (kk & 0x23) | ((kk & 0x0C) << 1) | ((kk & 0x10) >> 2);
#pragma unroll
      for (int ni = 0; ni < 4; ni++) {
        int col = n0 + wc * 64 + ni * 16 + fr;
        int h = col >> 6, d = col & 63;
        bf16x4 vv = (bf16x4){(bf16)acc[mi][ni][0], (bf16)acc[mi][ni][1],
                             (bf16)acc[mi][ni][2], (bf16)acc[mi][ni][3]};
        *(bf16x4*)&VTo[((size_t)(bI * H_ + h) * DH_ + d) * S_ + blk * 64 + slot] = vv;
      }
    }
  } else {
    bf16* O = z == 0 ? Qo : Ko;
    // Q: fold 1/sqrt(dh) AND log2(e) so softmax can use exp2 directly.
    float sc = (z == 0) ? 0.18033688011112042f : 1.0f;
#pragma unroll
    for (int mi = 0; mi < 4; mi++)
#pragma unroll
      for (int r = 0; r < 4; r++) {
        int row = m0 + wr * 64 + mi * 16 + 4 * fg + r;
        int b = row >> 11, s = row & 2047;
#pragma unroll
        for (int ni = 0; ni < 4; ni++) {
          int col = n0 + wc * 64 + ni * 16 + fr;
          int h = col >> 6, d = col & 63;
          O[((size_t)(b * H_ + h) * S_ + s) * DH_ + d] = (bf16)(acc[mi][ni][r] * sc);
        }
      }
  }
}

// ---------------- 3. flash attention (r12/r19-exact: measured 84.7us) -------
// 8 waves x 32 q-rows (block = 256 q, grid 512). KBLK=64, guarded dbuf
// staging, unroll-2 static offsets, defer-max (THR=7) per mi, l via
// ones-MFMA, v_max3 tree. XCD-swizzled (512 % 8 == 0).
__global__ __launch_bounds__(512, 4) void k_attn(const bf16* __restrict__ Q,
    const bf16* __restrict__ Kt, const bf16* __restrict__ VT, float* __restrict__ out) {
  __shared__ bf16 kv[16384];    // 32KB: buf0 [0,8192) K | [8192] V ; buf1 at +8192 elems
  int g = blockIdx.x;
  int wg = (g & 7) * 64 + (g >> 3);    // 512 % 8 == 0 -> bijective
  int qt = wg & 7, bh = wg >> 3;
  int b = bh >> 4, h = bh & 15;
  int tid = threadIdx.x, lane = tid & 63, w = tid >> 6;
  int fr = lane & 15, fg = lane >> 4;
  const char* Kb = (const char*)(Kt + (size_t)bh * S_ * DH_);
  const char* Vb = (const char*)(VT + (size_t)bh * DH_ * S_);
  int q0 = qt * 256 + w * 32;

  // per-thread staging sources (512 thr x 16B = 8KB per region per round)
  int o0 = tid * 16;                       // byte offset within region [0,8192)
  int r0 = o0 >> 7, b0 = (o0 & 127) ^ ((r0 & 7) << 4);
  const char* kp = Kb + r0 * 128 + b0;     // +8192 B/tile
  const char* vp = Vb + r0 * 4096 + b0;    // +128 B/tile
  char* lb = (char*)kv;
  int w1024 = w * 1024;                    // wave-uniform LDS dest base

  // hoisted LDS read bases: row = {ks,ds}*16 + fr -> row&7 == fr&7 loop-inv.
  const int swz = (fr & 7) << 3;
  const bf16* kb0 = &kv[fr * 64 + ((fg * 8) ^ swz)];
  const bf16* kb1 = &kv[fr * 64 + ((fg * 8 + 32) ^ swz)];
  const bf16* vb0 = kb0 + 4096;
  const bf16* vb1 = kb1 + 4096;

  bf16x8 qf[2][2];
#pragma unroll
  for (int mi = 0; mi < 2; mi++)
#pragma unroll
    for (int c = 0; c < 2; c++)
      qf[mi][c] = *(const bf16x8*)(Q + ((size_t)bh * S_ + q0 + mi * 16 + fr) * DH_ + fg * 8 + 32 * c);
  float m_[2] = {-1e30f, -1e30f};
  f32x4 o_[2][4];
#pragma unroll
  for (int mi = 0; mi < 2; mi++)
#pragma unroll
    for (int ds = 0; ds < 4; ds++) o_[mi][ds] = (f32x4){0.f, 0.f, 0.f, 0.f};
  f32x4 ol[2] = {(f32x4){0.f, 0.f, 0.f, 0.f}, (f32x4){0.f, 0.f, 0.f, 0.f}};
  bf16x8 vones;
#pragma unroll
  for (int j = 0; j < 8; j++) vones[j] = (bf16)1.0f;

  // prologue: stage tile 0 into buf0
  gload16(kp, lb + w1024);
  gload16(vp, lb + 8192 + w1024);
  kp += 8192; vp += 128;

#pragma unroll 2
  for (int kt = 0; kt < 32; ++kt) {
    __syncthreads();            // drains STAGE(kt); prior reads of buf^1 done
    if (kt + 1 < 32) {          // stage next tile; lands during compute below
      const int nb = ((kt + 1) & 1) << 14;
      gload16(kp, lb + nb + w1024);
      gload16(vp, lb + nb + 8192 + w1024);
      kp += 8192; vp += 128;
    }
    const int cb = (kt & 1) << 13;   // elems; compile-time under unroll 2
    // swapped QK^T: st[mi][ks] = D[key][q], col=q=fr, key = 16ks + 4fg + r
    f32x4 st[2][4];
    __builtin_amdgcn_s_setprio(1);
#pragma unroll
    for (int ks = 0; ks < 4; ks++) {
      bf16x8 kf0 = *(const bf16x8*)(kb0 + cb + ks * 1024);
      bf16x8 kf1 = *(const bf16x8*)(kb1 + cb + ks * 1024);
#pragma unroll
      for (int mi = 0; mi < 2; mi++) {
        f32x4 a = (f32x4){0.f, 0.f, 0.f, 0.f};
        a = __builtin_amdgcn_mfma_f32_16x16x32_bf16(kf0, qf[mi][0], a, 0, 0, 0);
        a = __builtin_amdgcn_mfma_f32_16x16x32_bf16(kf1, qf[mi][1], a, 0, 0, 0);
        st[mi][ks] = a;
      }
    }
    __builtin_amdgcn_s_setprio(0);
    // per-mi online softmax with defer-max (T13), v_max3 tree (T17)
    bf16x8 pa[2][2];
#pragma unroll
    for (int mi = 0; mi < 2; mi++) {
      float ma = fmaxf(fmaxf(st[mi][0][0], st[mi][0][1]), st[mi][0][2]);
      float mb = fmaxf(fmaxf(st[mi][0][3], st[mi][1][0]), st[mi][1][1]);
      float mc = fmaxf(fmaxf(st[mi][1][2], st[mi][1][3]), st[mi][2][0]);
      float md = fmaxf(fmaxf(st[mi][2][1], st[mi][2][2]), st[mi][2][3]);
      float me = fmaxf(fmaxf(st[mi][3][0], st[mi][3][1]), st[mi][3][2]);
      float mx = fmaxf(fmaxf(fmaxf(ma, mb), mc), fmaxf(fmaxf(md, me), st[mi][3][3]));
      mx = fmaxf(mx, __shfl_xor(mx, 16));
      mx = fmaxf(mx, __shfl_xor(mx, 32));
      if (!__all(mx - m_[mi] <= 7.0f)) {
        float mnew = fmaxf(m_[mi], mx);
        float sf = EXP2F(m_[mi] - mnew);
        m_[mi] = mnew;
        float s0 = __shfl(sf, 4 * fg + 0);
        float s1 = __shfl(sf, 4 * fg + 1);
        float s2 = __shfl(sf, 4 * fg + 2);
        float s3 = __shfl(sf, 4 * fg + 3);
#pragma unroll
        for (int ds = 0; ds < 4; ds++) {
          o_[mi][ds][0] *= s0; o_[mi][ds][1] *= s1;
          o_[mi][ds][2] *= s2; o_[mi][ds][3] *= s3;
        }
        ol[mi][0] *= s0; ol[mi][1] *= s1; ol[mi][2] *= s2; ol[mi][3] *= s3;
      }
#pragma unroll
      for (int ks = 0; ks < 4; ks++)
#pragma unroll
        for (int r = 0; r < 4; r++) st[mi][ks][r] = EXP2F(st[mi][ks][r] - m_[mi]);
      pa[mi][0] = (bf16x8){(bf16)st[mi][0][0], (bf16)st[mi][0][1], (bf16)st[mi][0][2],
                           (bf16)st[mi][0][3], (bf16)st[mi][1][0], (bf16)st[mi][1][1],
                           (bf16)st[mi][1][2], (bf16)st[mi][1][3]};
      pa[mi][1] = (bf16x8){(bf16)st[mi][2][0], (bf16)st[mi][2][1], (bf16)st[mi][2][2],
                           (bf16)st[mi][2][3], (bf16)st[mi][3][0], (bf16)st[mi][3][1],
                           (bf16)st[mi][3][2], (bf16)st[mi][3][3]};
    }
    // PV + row-sum(l) via ones-MFMA; V fragments SHARED across both mi
    __builtin_amdgcn_s_setprio(1);
#pragma unroll
    for (int mi = 0; mi < 2; mi++) {
      ol[mi] = __builtin_amdgcn_mfma_f32_16x16x32_bf16(pa[mi][0], vones, ol[mi], 0, 0, 0);
      ol[mi] = __builtin_amdgcn_mfma_f32_16x16x32_bf16(pa[mi][1], vones, ol[mi], 0, 0, 0);
    }
#pragma unroll
    for (int c = 0; c < 2; c++) {
      const bf16* vbc = c ? vb1 : vb0;
#pragma unroll
      for (int ds = 0; ds < 4; ds++) {
        bf16x8 vf = *(const bf16x8*)(vbc + cb + ds * 1024);
        o_[0][ds] = __builtin_amdgcn_mfma_f32_16x16x32_bf16(pa[0][c], vf, o_[0][ds], 0, 0, 0);
        o_[1][ds] = __builtin_amdgcn_mfma_f32_16x16x32_bf16(pa[1][c], vf, o_[1][ds], 0, 0, 0);
      }
    }
    __builtin_amdgcn_s_setprio(0);
  }
  // finalize: ol[mi][r] = l[q = q0+mi*16+4fg+r] (replicated over fr)
#pragma unroll
  for (int mi = 0; mi < 2; mi++)
#pragma unroll
    for (int r = 0; r < 4; r++) {
      float inv = 1.0f / ol[mi][r];
      int s = q0 + mi * 16 + 4 * fg + r;
#pragma unroll
      for (int ds = 0; ds < 4; ds++) {
        int col = h * DH_ + ds * 16 + fr;
        out[((size_t)b * S_ + s) * D_ + col] = o_[mi][ds][r] * inv;
      }
    }
}

extern "C" void kernel_launch(void* const* d_in, const int* in_sizes, int n_in,
                              void* d_out, int out_size, void* d_ws, size_t ws_size,
                              hipStream_t stream) {
  (void)in_sizes; (void)n_in; (void)out_size; (void)ws_size;
  const float* q  = (const float*)d_in[0];
  const float* k  = (const float*)d_in[1];
  const float* v  = (const float*)d_in[2];
  const float* wq = (const float*)d_in[3];
  const float* wk = (const float*)d_in[4];
  const float* wv = (const float*)d_in[5];
  float* out = (float*)d_out;
  char* ws = (char*)d_ws;
  size_t off = 0;
  bf16* wt = (bf16*)(ws + off); off += (size_t)3 * D_ * D_ * 2;    //  6.3 MB
  bf16* Qw = (bf16*)(ws + off); off += (size_t)BH_ * S_ * DH_ * 2; // 16.8 MB
  bf16* Kw = (bf16*)(ws + off); off += (size_t)BH_ * S_ * DH_ * 2;
  bf16* Vt = (bf16*)(ws + off); off += (size_t)BH_ * S_ * DH_ * 2;

  k_wt  <<<dim3(8, 32, 3), 256, 0, stream>>>(wq, wk, wv, wt);
  k_proj<<<dim3(64, 4, 3), 512, 0, stream>>>(q, k, v, wt, Qw, Kw, Vt);
  k_attn<<<dim3(512), 512, 0, stream>>>(Qw, Kw, Vt, out);
}